// Round 7
// baseline (31.932 us; speedup 1.0000x reference)
//
#include <hip/hip_runtime.h>

// ESN scan: out[b,c,t,r] = s_t, s_t = tanh(x[b,c,t]*w[r] + s_{t-1}*d[r]).
// B=32 C=8 T=512 R=256. 256 blocks x 256 threads, one thread per r-chain.
//
// R1: x staged in LDS -> no global loads in loop.            [34.6 -> 26.7]
// R2: exp2-chain shortened; stored value off-chain.          [neutral]
// R3: dwordx4 stores via block LDS transpose + barriers.     [-0.9us, reverted]
// R4: 2 chains/thread @ 2 waves/CU.                          [-5us; revealed
//     in-order issue: iter = 125(A stalls) + 24(B issue) = 149cy]
// R5: wide stores, wave-private LDS, no barriers.            [neutral]
// => All store structures identical => limiter = per-step dependent-chain
//    latency L~125cy (wall = 512*L, irreducible by parallelism).
// R6: cut L: rational tanh a*P(z)/Q(z) (Eigen minimax, |a|<=7.9, err ~1e-6).
//    Carried chain = {fma, med3, mul, 3-fma Q-Horner, rcp, fma} ~80cy; the
//    6-fma P-Horner overlaps the rcp latency; stored s = pa*rc off-chain.
//    ONE trans op on chain instead of two (exp2 AND rcp).

constexpr int Bdim = 32;
constexpr int Cdim = 8;
constexpr int Tdim = 512;
constexpr int Rdim = 256;
constexpr int T4   = Tdim / 4;   // 128 float4 of x per row

// Eigen generic_fast_tanh_float minimax coefficients: tanh(a) ~= a*P(a^2)/Q(a^2)
__device__ __forceinline__ float tanh_p(float z) {  // odd-part poly in z=a^2
    float p = fmaf(z, -2.76076847742355e-16f, 2.00018790482477e-13f);
    p = fmaf(z, p, -8.60467152213735e-11f);
    p = fmaf(z, p, 5.12229709037114e-08f);
    p = fmaf(z, p, 1.48572235717979e-05f * 0.0f + 1.48572235717979e-05f); // keep literal
    p = fmaf(z, p, 6.37261928875436e-04f);
    p = fmaf(z, p, 4.89352455891786e-03f);
    return p;
}
__device__ __forceinline__ float tanh_q(float z) {  // even-part poly
    float q = fmaf(z, 1.19825839466702e-06f, 1.18534705686654e-04f);
    q = fmaf(z, q, 2.26843463243900e-03f);
    q = fmaf(z, q, 4.89352518554385e-03f);
    return q;
}

__global__ __launch_bounds__(256, 1) void esn_scan_kernel(
    const float* __restrict__ x,     // [B*C, T]
    const float* __restrict__ W_in,  // [R] (R,1 flattened)
    const float* __restrict__ d,     // [R]
    float* __restrict__ out)         // [B*C, T, R]
{
    const int bc = blockIdx.x;
    const int r  = threadIdx.x;

    const float wc = W_in[r];   // input weight
    const float dc = d[r];      // recurrent weight

    __shared__ float4 xs4[T4];  // 2 KiB
    {
        const float4* __restrict__ x4 = reinterpret_cast<const float4*>(x + bc * Tdim);
        if (r < T4) xs4[r] = x4[r];
    }
    __syncthreads();

    float* __restrict__ o = out + (size_t)bc * Tdim * Rdim + r;

    // Group = 8 steps = 2 float4 of x; double-buffer groups in regs.
    float4 a0 = xs4[0], a1 = xs4[1];
    float4 b0 = xs4[2], b1 = xs4[3];

    float a = a0.x * wc;   // tanh argument at t=0 (s_init = 0)

    #pragma unroll 1
    for (int g = 0; g < Tdim / 8; ++g) {
        int pf = 2 * g + 4; if (pf > T4 - 2) pf = T4 - 2;
        float4 c0 = xs4[pf], c1 = xs4[pf + 1];

        // Off-chain: pre[j] = x_{t+1} * w (successor argument's input part).
        float pre[8];
        pre[0] = a0.y * wc;
        pre[1] = a0.z * wc;
        pre[2] = a0.w * wc;
        pre[3] = a1.x * wc;
        pre[4] = a1.y * wc;
        pre[5] = a1.z * wc;
        pre[6] = a1.w * wc;
        pre[7] = b0.x * wc;   // next group's t0 (dead on last group)

        float* ob  = o + (size_t)(g * 8) * Rdim;   // steps 0..3
        float* ob4 = ob + (size_t)4 * Rdim;        // steps 4..7 (imm < 4096B)

        #pragma unroll
        for (int j = 0; j < 8; ++j) {
            float z  = a * a;
            float p  = tanh_p(z);           // 6 fmas, overlaps rcp below
            float q  = tanh_q(z);           // 3 fmas (on chain)
            float rc = __builtin_amdgcn_rcpf(q);
            float pa = p * a;
            float s  = pa * rc;             // tanh(a) — store value, off chain
            if (j < 4) ob[j * Rdim] = s;
            else       ob4[(j - 4) * Rdim] = s;
            // carried: a' = d*s + pre = fma(d*pa, rc, pre)
            a = fmaf(pa * dc, rc, pre[j]);
            // safety clamp to the rational's valid range (|a|<=6 in practice)
            a = fminf(7.90531f, fmaxf(-7.90531f, a));
        }

        a0 = b0; a1 = b1;
        b0 = c0; b1 = c1;
    }
}

extern "C" void kernel_launch(void* const* d_in, const int* in_sizes, int n_in,
                              void* d_out, int out_size, void* d_ws, size_t ws_size,
                              hipStream_t stream) {
    const float* x    = (const float*)d_in[0];  // [B,C,T]
    const float* W_in = (const float*)d_in[1];  // [R,1]
    const float* d    = (const float*)d_in[2];  // [R]
    float* out        = (float*)d_out;          // [B,C,T,R]

    dim3 grid(Bdim * Cdim);
    dim3 block(Rdim);
    esn_scan_kernel<<<grid, block, 0, stream>>>(x, W_in, d, out);
}